// Round 1
// baseline (171.879 us; speedup 1.0000x reference)
//
#include <hip/hip_runtime.h>
#include <math.h>

#define NEG_SLOPE 0.2f
#define LN_EPS 1e-5f

constexpr int B = 64, A = 256, L = 1024, D = 128;

// ---------------------------------------------------------------------------
// prep: u[d] = sum_e W_mol[d][e] * w_align_mol[e];  c0 = b_mol.w_align_mol + b_align
// ---------------------------------------------------------------------------
__global__ void prep_kernel(const float* __restrict__ W_mol,
                            const float* __restrict__ b_mol,
                            const float* __restrict__ w_align_mol,
                            const float* __restrict__ b_align,
                            float* __restrict__ u, float* __restrict__ c0) {
    int d = threadIdx.x;
    const float* row = W_mol + d * D;
    float s = 0.f;
    for (int e = 0; e < D; ++e) s += row[e] * w_align_mol[e];
    u[d] = s;
    if (d == 0) {
        float c = 0.f;
        for (int e = 0; e < D; ++e) c += b_mol[e] * w_align_mol[e];
        *c0 = c + b_align[0];
    }
}

// ---------------------------------------------------------------------------
// nb_gemm: atm[r][:] = atom[r][:] @ W + bias ; s_atm[r] = atm[r][:] . wa
// Block: 256 threads, 128 rows x 128 cols tile. X transposed in LDS.
// Thread (tr,tc): rows tr*16..+15, cols tc*4..+3  (16x4 = 64 acc regs)
// ---------------------------------------------------------------------------
__global__ __launch_bounds__(256) void nb_gemm_kernel(
    const float* __restrict__ atom, const float* __restrict__ W,
    const float* __restrict__ bias, const float* __restrict__ wa,
    float* __restrict__ atm, float* __restrict__ s_atm) {
    __shared__ float Xs[D][136];   // Xs[d][r], padded stride (16B aligned)
    const int tid = threadIdx.x;
    const int R0 = blockIdx.x * 128;

    // stage X transposed: lane d coalesced per source row, float4 write along r
    {
        int d = tid & 127;
        int rg = tid >> 7;   // 0..1
        #pragma unroll
        for (int g = 0; g < 16; ++g) {
            int r0 = (g * 2 + rg) * 4;
            float4 v;
            v.x = atom[(size_t)(R0 + r0 + 0) * D + d];
            v.y = atom[(size_t)(R0 + r0 + 1) * D + d];
            v.z = atom[(size_t)(R0 + r0 + 2) * D + d];
            v.w = atom[(size_t)(R0 + r0 + 3) * D + d];
            *(float4*)&Xs[d][r0] = v;
        }
    }
    __syncthreads();

    const int tc = tid & 31;
    const int tr = tid >> 5;
    float4 bv = *(const float4*)&bias[tc * 4];
    float acc[16][4];
    #pragma unroll
    for (int i = 0; i < 16; ++i) {
        acc[i][0] = bv.x; acc[i][1] = bv.y; acc[i][2] = bv.z; acc[i][3] = bv.w;
    }

    #pragma unroll 2
    for (int d = 0; d < D; ++d) {
        float4 w = *(const float4*)&W[d * D + tc * 4];   // L1/L2 resident (64KB total)
        float xv[16];
        *(float4*)&xv[0]  = *(const float4*)&Xs[d][tr * 16 + 0];
        *(float4*)&xv[4]  = *(const float4*)&Xs[d][tr * 16 + 4];
        *(float4*)&xv[8]  = *(const float4*)&Xs[d][tr * 16 + 8];
        *(float4*)&xv[12] = *(const float4*)&Xs[d][tr * 16 + 12];
        #pragma unroll
        for (int i = 0; i < 16; ++i) {
            acc[i][0] += xv[i] * w.x; acc[i][1] += xv[i] * w.y;
            acc[i][2] += xv[i] * w.z; acc[i][3] += xv[i] * w.w;
        }
    }

    float4 wav = *(const float4*)&wa[tc * 4];
    #pragma unroll
    for (int i = 0; i < 16; ++i) {
        int r = R0 + tr * 16 + i;
        float4 o; o.x = acc[i][0]; o.y = acc[i][1]; o.z = acc[i][2]; o.w = acc[i][3];
        *(float4*)&atm[(size_t)r * D + tc * 4] = o;
        float p = o.x * wav.x + o.y * wav.y + o.z * wav.z + o.w * wav.w;
        p += __shfl_xor(p, 1);  p += __shfl_xor(p, 2);  p += __shfl_xor(p, 4);
        p += __shfl_xor(p, 8);  p += __shfl_xor(p, 16);
        if (tc == 0) s_atm[r] = p;   // lanes 0 and 32 write their tr-group's rows
    }
}

// ---------------------------------------------------------------------------
// attn: per block = one batch b, 16 fragment rows.
//   phase0: s_mol (dot with u), phase1: scores+softmax -> attn LDS,
//   phase2: PV (ctx = attn @ atm[b]), phase3: LayerNorm -> out
// ---------------------------------------------------------------------------
__global__ __launch_bounds__(256) void attn_kernel(
    const float* __restrict__ molf,    // [B][A][D]
    const float* __restrict__ amask,   // [B][A]
    const float* __restrict__ smask,   // [B][L]
    const float* __restrict__ atm,     // [B][L][D]
    const float* __restrict__ s_atm,   // [B][L]
    const float* __restrict__ u, const float* __restrict__ c0p,
    const float* __restrict__ gamma, const float* __restrict__ beta,
    float* __restrict__ out) {
    __shared__ float attnL[16][L];     // 64 KB (unnormalized softmax numerators)
    __shared__ float ctxL[16][D];      // 8 KB
    __shared__ float s_molL[16];
    __shared__ float scaleL[16];       // attend_mask / sum

    // XCD-bijective swizzle (nwg=1024, 8 XCDs): blocks sharing b -> same XCD L2
    const int bid = blockIdx.x;
    const int lid = (bid & 7) * 128 + (bid >> 3);
    const int b  = lid >> 4;
    const int a0 = (lid & 15) * 16;
    const int tid = threadIdx.x;
    const int lane = tid & 63;
    const int w = tid >> 6;

    // phase 0: s_mol for the 16 rows (16 lanes per row, 8 elems each)
    {
        int r = tid >> 4;
        int q = tid & 15;
        const float* x = molf + ((size_t)b * A + a0 + r) * D + q * 8;
        float4 xa = *(const float4*)x;
        float4 xb = *(const float4*)(x + 4);
        float4 ua = *(const float4*)&u[q * 8];
        float4 ub = *(const float4*)&u[q * 8 + 4];
        float p = xa.x * ua.x + xa.y * ua.y + xa.z * ua.z + xa.w * ua.w
                + xb.x * ub.x + xb.y * ub.y + xb.z * ub.z + xb.w * ub.w;
        p += __shfl_xor(p, 1); p += __shfl_xor(p, 2);
        p += __shfl_xor(p, 4); p += __shfl_xor(p, 8);
        if (q == 0) s_molL[r] = p + c0p[0];
    }
    __syncthreads();

    // phase 1: scores + softmax, 4 rows per wave, 16 score elems per lane
    {
        const float* sAt = s_atm + (size_t)b * L;
        const float* msk = smask + (size_t)b * L;
        float sAtv[16], mskv[16];
        #pragma unroll
        for (int k = 0; k < 16; ++k) {
            sAtv[k] = sAt[lane + 64 * k];
            mskv[k] = msk[lane + 64 * k];
        }
        for (int j = 0; j < 4; ++j) {
            int r = w * 4 + j;
            float sm = s_molL[r];
            float s[16];
            float mx = -3.0e38f;
            #pragma unroll
            for (int k = 0; k < 16; ++k) {
                float t = sm + sAtv[k];
                t = (t > 0.f) ? t : NEG_SLOPE * t;   // leaky_relu BEFORE mask
                t += mskv[k];
                s[k] = t;
                mx = fmaxf(mx, t);
            }
            #pragma unroll
            for (int o = 1; o < 64; o <<= 1) mx = fmaxf(mx, __shfl_xor(mx, o));
            float sum = 0.f;
            #pragma unroll
            for (int k = 0; k < 16; ++k) {
                float p = __expf(s[k] - mx);
                sum += p;
                attnL[r][lane + 64 * k] = p;
            }
            #pragma unroll
            for (int o = 1; o < 64; o <<= 1) sum += __shfl_xor(sum, o);
            if (lane == 0) scaleL[r] = amask[(size_t)b * A + a0 + r] / sum;
        }
    }
    __syncthreads();

    // phase 2: PV. thread = (rr, dq): rows {rr, rr+8}, cols dq*4..+3
    {
        const float* atmB = atm + (size_t)b * L * D;
        const int dq = tid & 31;
        const int rr = tid >> 5;
        float4 acc0 = {0, 0, 0, 0}, acc1 = {0, 0, 0, 0};
        #pragma unroll 2
        for (int l = 0; l < L; l += 4) {
            float4 p0 = *(const float4*)&attnL[rr][l];
            float4 p1 = *(const float4*)&attnL[rr + 8][l];
            const float* pa = (const float*)&p0;
            const float* pb = (const float*)&p1;
            #pragma unroll
            for (int q = 0; q < 4; ++q) {
                float4 av = *(const float4*)&atmB[(size_t)(l + q) * D + dq * 4];
                acc0.x += pa[q] * av.x; acc0.y += pa[q] * av.y;
                acc0.z += pa[q] * av.z; acc0.w += pa[q] * av.w;
                acc1.x += pb[q] * av.x; acc1.y += pb[q] * av.y;
                acc1.z += pb[q] * av.z; acc1.w += pb[q] * av.w;
            }
        }
        float s0 = scaleL[rr], s1 = scaleL[rr + 8];
        float4 o0 = {acc0.x * s0, acc0.y * s0, acc0.z * s0, acc0.w * s0};
        float4 o1 = {acc1.x * s1, acc1.y * s1, acc1.z * s1, acc1.w * s1};
        *(float4*)&ctxL[rr][dq * 4] = o0;
        *(float4*)&ctxL[rr + 8][dq * 4] = o1;
    }
    __syncthreads();

    // phase 3: LayerNorm over D, 4 rows per wave, 2 elems per lane
    #pragma unroll
    for (int j = 0; j < 4; ++j) {
        int r = w * 4 + j;
        float x0 = ctxL[r][lane], x1 = ctxL[r][64 + lane];
        float sm2 = x0 + x1;
        float sq = x0 * x0 + x1 * x1;
        #pragma unroll
        for (int o = 1; o < 64; o <<= 1) {
            sm2 += __shfl_xor(sm2, o);
            sq  += __shfl_xor(sq, o);
        }
        float mu = sm2 * (1.f / 128.f);
        float var = sq * (1.f / 128.f) - mu * mu;
        float rs = rsqrtf(var + LN_EPS);
        size_t base = ((size_t)b * A + a0 + r) * D;
        out[base + lane]      = (x0 - mu) * rs * gamma[lane] + beta[lane];
        out[base + 64 + lane] = (x1 - mu) * rs * gamma[64 + lane] + beta[64 + lane];
    }
}

// ---------------------------------------------------------------------------
extern "C" void kernel_launch(void* const* d_in, const int* in_sizes, int n_in,
                              void* d_out, int out_size, void* d_ws, size_t ws_size,
                              hipStream_t stream) {
    const float* molf  = (const float*)d_in[0];
    const float* atomf = (const float*)d_in[1];
    const float* amask = (const float*)d_in[2];
    const float* smask = (const float*)d_in[3];
    const float* W_mol = (const float*)d_in[4];
    const float* b_mol = (const float*)d_in[5];
    const float* W_nb  = (const float*)d_in[6];
    const float* b_nb  = (const float*)d_in[7];
    const float* w_am  = (const float*)d_in[8];
    const float* w_aa  = (const float*)d_in[9];
    const float* b_al  = (const float*)d_in[10];
    const float* gamma = (const float*)d_in[11];
    const float* beta  = (const float*)d_in[12];
    float* out = (float*)d_out;

    // workspace layout (floats): atm [B*L*D] | s_atm [B*L] | u [D] | c0 [1]
    float* atm_ws   = (float*)d_ws;
    float* s_atm_ws = atm_ws + (size_t)B * L * D;
    float* u_ws     = s_atm_ws + (size_t)B * L;
    float* c0_ws    = u_ws + D;

    prep_kernel<<<1, 128, 0, stream>>>(W_mol, b_mol, w_am, b_al, u_ws, c0_ws);
    nb_gemm_kernel<<<(B * L) / 128, 256, 0, stream>>>(atomf, W_nb, b_nb, w_aa,
                                                      atm_ws, s_atm_ws);
    attn_kernel<<<B * (A / 16), 256, 0, stream>>>(molf, amask, smask, atm_ws,
                                                  s_atm_ws, u_ws, c0_ws,
                                                  gamma, beta, out);
}

// Round 2
// 86.384 us; speedup vs baseline: 1.9897x; 1.9897x over previous
//
#include <hip/hip_runtime.h>
#include <hip/hip_bf16.h>
#include <math.h>

#define NEG_SLOPE 0.2f
#define LN_EPS 1e-5f

constexpr int B = 64, A = 256, L = 1024, D = 128;

typedef float f32x4 __attribute__((ext_vector_type(4)));
typedef short bf16x8 __attribute__((ext_vector_type(8)));

__device__ __forceinline__ ushort f2bf(float x) {
    __hip_bfloat16 h = __float2bfloat16(x);
    return *reinterpret_cast<ushort*>(&h);
}
// 16B-chunk XOR swizzle: rows (d) spread across chunk slots -> conflict-free b128
__device__ __forceinline__ int sw16(int d, int c) {
    return c ^ (((d & 7) << 1) | ((d >> 3) & 1));
}

// ---------------------------------------------------------------------------
// prep: u = W_mol @ w_align_mol ; c0 = b_mol.w_align_mol + b_align
// ---------------------------------------------------------------------------
__global__ void prep_kernel(const float* __restrict__ W_mol,
                            const float* __restrict__ b_mol,
                            const float* __restrict__ w_align_mol,
                            const float* __restrict__ b_align,
                            float* __restrict__ u, float* __restrict__ c0) {
    int d = threadIdx.x;
    const float* row = W_mol + d * D;
    float s = 0.f;
    for (int e = 0; e < D; ++e) s += row[e] * w_align_mol[e];
    u[d] = s;
    if (d == 0) {
        float c = 0.f;
        for (int e = 0; e < D; ++e) c += b_mol[e] * w_align_mol[e];
        *c0 = c + b_align[0];
    }
}

// ---------------------------------------------------------------------------
// nb_gemm: atm = atom @ W + bias (fp32 regs) ->
//   writes atmT bf16 [B][D][L] (LDS-transposed, swizzle-staged, coalesced)
//   + softmax tables: s_atmM (masked), e_l = valid?exp(s):0, f_l = valid?exp(.2s):0
// ---------------------------------------------------------------------------
__global__ __launch_bounds__(256) void nb_gemm_kernel(
    const float* __restrict__ atom, const float* __restrict__ W,
    const float* __restrict__ bias, const float* __restrict__ wa,
    const float* __restrict__ smask,
    ushort* __restrict__ atmT, float* __restrict__ s_atmM,
    float* __restrict__ e_l, float* __restrict__ f_l) {
    __shared__ float Xs[D][136];   // also reused (32KB) for bf16 transpose staging
    const int tid = threadIdx.x;
    const int R0 = blockIdx.x * 128;

    {   // stage X transposed: Xs[d][r]
        int d = tid & 127;
        int rg = tid >> 7;
        #pragma unroll
        for (int g = 0; g < 16; ++g) {
            int r0 = (g * 2 + rg) * 4;
            float4 v;
            v.x = atom[(size_t)(R0 + r0 + 0) * D + d];
            v.y = atom[(size_t)(R0 + r0 + 1) * D + d];
            v.z = atom[(size_t)(R0 + r0 + 2) * D + d];
            v.w = atom[(size_t)(R0 + r0 + 3) * D + d];
            *(float4*)&Xs[d][r0] = v;
        }
    }
    __syncthreads();

    const int tc = tid & 31;
    const int tr = tid >> 5;
    float4 bv = *(const float4*)&bias[tc * 4];
    float acc[16][4];
    #pragma unroll
    for (int i = 0; i < 16; ++i) {
        acc[i][0] = bv.x; acc[i][1] = bv.y; acc[i][2] = bv.z; acc[i][3] = bv.w;
    }

    #pragma unroll 2
    for (int d = 0; d < D; ++d) {
        float4 w = *(const float4*)&W[d * D + tc * 4];
        float xv[16];
        *(float4*)&xv[0]  = *(const float4*)&Xs[d][tr * 16 + 0];
        *(float4*)&xv[4]  = *(const float4*)&Xs[d][tr * 16 + 4];
        *(float4*)&xv[8]  = *(const float4*)&Xs[d][tr * 16 + 8];
        *(float4*)&xv[12] = *(const float4*)&Xs[d][tr * 16 + 12];
        #pragma unroll
        for (int i = 0; i < 16; ++i) {
            acc[i][0] += xv[i] * w.x; acc[i][1] += xv[i] * w.y;
            acc[i][2] += xv[i] * w.z; acc[i][3] += xv[i] * w.w;
        }
    }

    // s_atm + softmax tables (fp32 accuracy)
    float4 wav = *(const float4*)&wa[tc * 4];
    #pragma unroll
    for (int i = 0; i < 16; ++i) {
        float p = acc[i][0] * wav.x + acc[i][1] * wav.y
                + acc[i][2] * wav.z + acc[i][3] * wav.w;
        p += __shfl_xor(p, 1);  p += __shfl_xor(p, 2);  p += __shfl_xor(p, 4);
        p += __shfl_xor(p, 8);  p += __shfl_xor(p, 16);
        if (tc == 0) {
            int r = R0 + tr * 16 + i;
            float sm = smask[r];
            bool val = sm > -0.5f;
            s_atmM[r] = val ? p : -1e30f;
            e_l[r]    = val ? __expf(p) : 0.f;
            f_l[r]    = val ? __expf(NEG_SLOPE * p) : 0.f;
        }
    }

    __syncthreads();   // done reading Xs; reuse as bf16 transpose buffer
    ushort* tb = (ushort*)&Xs[0][0];   // [128 d][128 l] bf16, 16B-chunk swizzled
    #pragma unroll
    for (int c = 0; c < 4; ++c) {
        int d = tc * 4 + c;
        alignas(16) ushort tmp[16];
        #pragma unroll
        for (int i = 0; i < 16; ++i) tmp[i] = f2bf(acc[i][c]);
        #pragma unroll
        for (int h = 0; h < 2; ++h) {
            int ch = sw16(d, tr * 2 + h);
            *(int4*)((char*)tb + d * 256 + ch * 16) = *(int4*)&tmp[h * 8];
        }
    }
    __syncthreads();
    {   // coalesced global write of atmT[b][d][l-slice]
        int c = tid & 15, db = tid >> 4;
        int b_ = R0 >> 10, l0 = R0 & 1023;
        #pragma unroll
        for (int j = 0; j < 8; ++j) {
            int d = db + j * 16;
            int4 v = *(int4*)((char*)tb + d * 256 + sw16(d, c) * 16);
            *(int4*)&atmT[((size_t)(b_ * D + d)) * L + l0 + c * 8] = v;
        }
    }
}

// ---------------------------------------------------------------------------
// attn: block = (b, 64 fragment rows). Separable softmax (no per-pair exp),
// PV via mfma_16x16x32_bf16: ctx^T[d][a] = sum_l atmT[d][l] * p[l][a].
// ---------------------------------------------------------------------------
__global__ __launch_bounds__(256) void attn_kernel(
    const float* __restrict__ molf, const float* __restrict__ amask,
    const ushort* __restrict__ atmT,
    const float* __restrict__ s_atmM_g, const float* __restrict__ e_lG,
    const float* __restrict__ f_lG,
    const float* __restrict__ u, const float* __restrict__ c0p,
    const float* __restrict__ gamma, const float* __restrict__ beta,
    float* __restrict__ out) {
    __shared__ float sL[L], eL[L], fL[L];          // 12 KB softmax tables
    __shared__ float thL[64], eaL[64], faL[64];    // per-row consts
    __shared__ float wmaxL[4];
    __shared__ float gbL[256];                     // gamma | beta
    __shared__ int4 tileI[2][2048];                // 2 x 32 KB atmT tiles (swizzled)

    const int bid = blockIdx.x;
    const int lid = (bid & 7) * 32 + (bid >> 3);   // XCD swizzle (256%8==0, bijective)
    const int b  = lid >> 2;
    const int at = lid & 3;
    const int tid = threadIdx.x;
    const int w = tid >> 6, lane = tid & 63;
    const int la = lane & 15, kg = lane >> 4;

    // phase 0a: load tables + gamma/beta, find M_b = max valid s_atm
    {
        int i4 = tid * 4;
        float4 sa = *(const float4*)&s_atmM_g[(size_t)b * L + i4];
        *(float4*)&sL[i4] = sa;
        *(float4*)&eL[i4] = *(const float4*)&e_lG[(size_t)b * L + i4];
        *(float4*)&fL[i4] = *(const float4*)&f_lG[(size_t)b * L + i4];
        if (tid < 32)      ((float4*)gbL)[tid] = ((const float4*)gamma)[tid];
        else if (tid < 64) ((float4*)gbL)[tid] = ((const float4*)beta)[tid - 32];
        float mx = fmaxf(fmaxf(sa.x, sa.y), fmaxf(sa.z, sa.w));
        #pragma unroll
        for (int o = 1; o < 64; o <<= 1) mx = fmaxf(mx, __shfl_xor(mx, o));
        if (lane == 0) wmaxL[w] = mx;
    }
    __syncthreads();

    // phase 0b: s_mol + per-row softmax constants (4 threads per row)
    {
        float M = fmaxf(fmaxf(wmaxL[0], wmaxL[1]), fmaxf(wmaxL[2], wmaxL[3]));
        int r = tid >> 2, q = tid & 3;
        const float* x = molf + ((size_t)b * A + at * 64 + r) * D + q * 32;
        float p = 0.f;
        #pragma unroll
        for (int k = 0; k < 8; ++k) {
            float4 xv = *(const float4*)&x[k * 4];
            float4 uv = *(const float4*)&u[q * 32 + k * 4];
            p += xv.x * uv.x + xv.y * uv.y + xv.z * uv.z + xv.w * uv.w;
        }
        p += __shfl_xor(p, 1); p += __shfl_xor(p, 2);
        if (q == 0) {
            float sm = p + c0p[0];
            float z = sm + M;
            float m = (z > 0.f) ? z : NEG_SLOPE * z;   // exact row max
            thL[r] = -sm;
            eaL[r] = __expf(sm - m);
            faL[r] = __expf(NEG_SLOPE * sm - m);
        }
    }

    // prologue: stage tile 0
    const ushort* atmTb = atmT + (size_t)b * D * L;
    const int c = tid & 15, db = tid >> 4;
    int4 pre[8];
    #pragma unroll
    for (int j = 0; j < 8; ++j)
        pre[j] = *(const int4*)&atmTb[(size_t)(db + j * 16) * L + c * 8];
    __syncthreads();   // also covers phase-0b LDS writes
    #pragma unroll
    for (int j = 0; j < 8; ++j) {
        int d = db + j * 16;
        *(int4*)((char*)tileI[0] + d * 256 + sw16(d, c) * 16) = pre[j];
    }
    __syncthreads();

    const float ea = eaL[w * 16 + la];
    const float fa = faL[w * 16 + la];
    const float th = thL[w * 16 + la];
    f32x4 acc[8] = {};
    float psum = 0.f;

    for (int t = 0; t < 8; ++t) {
        if (t < 7) {
            #pragma unroll
            for (int j = 0; j < 8; ++j)
                pre[j] = *(const int4*)&atmTb[(size_t)(db + j * 16) * L
                                              + (t + 1) * 128 + c * 8];
        }
        const char* buf = (const char*)tileI[t & 1];
        #pragma unroll
        for (int ks = 0; ks < 4; ++ks) {
            int lbase = t * 128 + ks * 32 + kg * 8;
            float sv[8], ev[8], fv[8];
            *(float4*)&sv[0] = *(const float4*)&sL[lbase];
            *(float4*)&sv[4] = *(const float4*)&sL[lbase + 4];
            *(float4*)&ev[0] = *(const float4*)&eL[lbase];
            *(float4*)&ev[4] = *(const float4*)&eL[lbase + 4];
            *(float4*)&fv[0] = *(const float4*)&fL[lbase];
            *(float4*)&fv[4] = *(const float4*)&fL[lbase + 4];
            bf16x8 bfrag;
            #pragma unroll
            for (int j = 0; j < 8; ++j) {
                float p = (sv[j] > th) ? ea * ev[j] : fa * fv[j];
                psum += p;
                bfrag[j] = (short)f2bf(p);
            }
            #pragma unroll
            for (int dt = 0; dt < 8; ++dt) {
                int d = dt * 16 + la;
                bf16x8 afrag = *(const bf16x8*)(buf + d * 256
                                                + sw16(d, ks * 4 + kg) * 16);
                acc[dt] = __builtin_amdgcn_mfma_f32_16x16x32_bf16(
                    afrag, bfrag, acc[dt], 0, 0, 0);
            }
        }
        if (t < 7) {
            char* nbuf = (char*)tileI[(t + 1) & 1];
            #pragma unroll
            for (int j = 0; j < 8; ++j) {
                int d = db + j * 16;
                *(int4*)(nbuf + d * 256 + sw16(d, c) * 16) = pre[j];
            }
        }
        __syncthreads();
    }

    // epilogue: normalize + attend mask + LayerNorm, all in registers
    psum += __shfl_xor(psum, 16);
    psum += __shfl_xor(psum, 32);
    const int aG = at * 64 + w * 16 + la;
    const float scale = amask[(size_t)b * A + aG] / psum;
    float v[8][4];
    float s1 = 0.f, s2 = 0.f;
    #pragma unroll
    for (int dt = 0; dt < 8; ++dt)
        #pragma unroll
        for (int r = 0; r < 4; ++r) {
            float x = acc[dt][r] * scale;
            v[dt][r] = x; s1 += x; s2 += x * x;
        }
    s1 += __shfl_xor(s1, 16); s1 += __shfl_xor(s1, 32);
    s2 += __shfl_xor(s2, 16); s2 += __shfl_xor(s2, 32);
    const float mu = s1 * (1.f / 128.f);
    const float var = s2 * (1.f / 128.f) - mu * mu;
    const float rs = rsqrtf(var + LN_EPS);
    const size_t obase = ((size_t)b * A + aG) * D;
    #pragma unroll
    for (int dt = 0; dt < 8; ++dt) {
        int d0 = dt * 16 + kg * 4;
        float4 g4 = *(float4*)&gbL[d0];
        float4 b4 = *(float4*)&gbL[128 + d0];
        float4 o;
        o.x = (v[dt][0] - mu) * rs * g4.x + b4.x;
        o.y = (v[dt][1] - mu) * rs * g4.y + b4.y;
        o.z = (v[dt][2] - mu) * rs * g4.z + b4.z;
        o.w = (v[dt][3] - mu) * rs * g4.w + b4.w;
        *(float4*)&out[obase + d0] = o;
    }
}

// ---------------------------------------------------------------------------
extern "C" void kernel_launch(void* const* d_in, const int* in_sizes, int n_in,
                              void* d_out, int out_size, void* d_ws, size_t ws_size,
                              hipStream_t stream) {
    const float* molf  = (const float*)d_in[0];
    const float* atomf = (const float*)d_in[1];
    const float* amask = (const float*)d_in[2];
    const float* smask = (const float*)d_in[3];
    const float* W_mol = (const float*)d_in[4];
    const float* b_mol = (const float*)d_in[5];
    const float* W_nb  = (const float*)d_in[6];
    const float* b_nb  = (const float*)d_in[7];
    const float* w_am  = (const float*)d_in[8];
    const float* w_aa  = (const float*)d_in[9];
    const float* b_al  = (const float*)d_in[10];
    const float* gamma = (const float*)d_in[11];
    const float* beta  = (const float*)d_in[12];
    float* out = (float*)d_out;

    // ws: atmT bf16 [B*D*L] | s_atmM | e_l | f_l [B*L] | u [D] | c0
    ushort* atmT   = (ushort*)d_ws;
    float* s_atmM  = (float*)(atmT + (size_t)B * D * L);
    float* e_l     = s_atmM + (size_t)B * L;
    float* f_l     = e_l + (size_t)B * L;
    float* u_ws    = f_l + (size_t)B * L;
    float* c0_ws   = u_ws + D;

    prep_kernel<<<1, 128, 0, stream>>>(W_mol, b_mol, w_am, b_al, u_ws, c0_ws);
    nb_gemm_kernel<<<(B * L) / 128, 256, 0, stream>>>(atomf, W_nb, b_nb, w_aa,
                                                      smask, atmT, s_atmM, e_l, f_l);
    attn_kernel<<<B * (A / 64), 256, 0, stream>>>(molf, amask, atmT, s_atmM, e_l,
                                                  f_l, u_ws, c0_ws, gamma, beta, out);
}

// Round 3
// 80.543 us; speedup vs baseline: 2.1340x; 1.0725x over previous
//
#include <hip/hip_runtime.h>
#include <hip/hip_bf16.h>
#include <math.h>

#define NEG_SLOPE 0.2f
#define LN_EPS 1e-5f

constexpr int B = 64, A = 256, L = 1024, D = 128;

typedef float f32x4 __attribute__((ext_vector_type(4)));
typedef short bf16x8 __attribute__((ext_vector_type(8)));

__device__ __forceinline__ ushort f2bf(float x) {
    __hip_bfloat16 h = __float2bfloat16(x);
    return *reinterpret_cast<ushort*>(&h);
}
// 16B-chunk XOR swizzle for the attn LDS tile (conflict-free b128)
__device__ __forceinline__ int sw16(int d, int c) {
    return c ^ (((d & 7) << 1) | ((d >> 3) & 1));
}

// ---------------------------------------------------------------------------
// prep: u = W_mol @ w_align_mol ; c0 = b_mol.w_align_mol + b_align ;
//       WT[d][e] = bf16(W_nb[e][d])
// ---------------------------------------------------------------------------
__global__ void prep_kernel(const float* __restrict__ Wmol, const float* __restrict__ bmol,
                            const float* __restrict__ wam, const float* __restrict__ bal,
                            const float* __restrict__ Wnb,
                            float* __restrict__ u, float* __restrict__ c0,
                            ushort* __restrict__ WT) {
    __shared__ float red[2], red2[2];
    const int d = blockIdx.x, e = threadIdx.x;   // 128 blocks x 128 threads
    const int lane = e & 63, wv = e >> 6;
    float p = Wmol[d * D + e] * wam[e];
    #pragma unroll
    for (int o = 1; o < 64; o <<= 1) p += __shfl_xor(p, o);
    WT[d * D + e] = f2bf(Wnb[e * D + d]);
    float q = 0.f;
    if (d == 0) q = bmol[e] * wam[e];
    #pragma unroll
    for (int o = 1; o < 64; o <<= 1) q += __shfl_xor(q, o);
    if (lane == 0) { red[wv] = p; red2[wv] = q; }
    __syncthreads();
    if (e == 0) {
        u[d] = red[0] + red[1];
        if (d == 0) c0[0] = red2[0] + red2[1] + bal[0];
    }
}

// ---------------------------------------------------------------------------
// nb_gemm v3 (MFMA): per block 128 rows. atm = atom @ W + b via
// mfma_16x16x32_bf16 with A = atom rows (global fp32 -> bf16 regs),
// B = WT rows (bf16 global, L1-resident). C layout [l][d]: lane holds
// 4 consecutive l per reg -> 8B LDS bounce writes -> coalesced atmT[d][l].
// Epilogue computes softmax tables from fp32 acc.
// ---------------------------------------------------------------------------
__global__ __launch_bounds__(256) void nb_gemm_kernel(
    const float* __restrict__ atom, const ushort* __restrict__ WT,
    const float* __restrict__ bias, const float* __restrict__ wa,
    const float* __restrict__ smask,
    ushort* __restrict__ atmT, float* __restrict__ s_atmM,
    float* __restrict__ e_l, float* __restrict__ f_l) {
    __shared__ ushort tb[128][136];   // [d][l] bounce, padded (2-way max)
    const int tid = threadIdx.x;
    const int wv = tid >> 6, lane = tid & 63, la = lane & 15, kg = lane >> 4;
    const int R0 = blockIdx.x * 128;
    const int b = R0 >> 10, l0 = R0 & 1023;

    float wav[8], bv[8];
    #pragma unroll
    for (int dt = 0; dt < 8; ++dt) { wav[dt] = wa[dt * 16 + la]; bv[dt] = bias[dt * 16 + la]; }

    #pragma unroll
    for (int s = 0; s < 2; ++s) {
        const int lt = wv * 32 + s * 16;           // local l-tile base (0..127)
        const float* arow = atom + (size_t)(R0 + lt + la) * D + kg * 8;
        bf16x8 af[4];
        #pragma unroll
        for (int ks = 0; ks < 4; ++ks) {
            float4 x0 = *(const float4*)&arow[ks * 32];
            float4 x1 = *(const float4*)&arow[ks * 32 + 4];
            bf16x8 t;
            t[0] = (short)f2bf(x0.x); t[1] = (short)f2bf(x0.y);
            t[2] = (short)f2bf(x0.z); t[3] = (short)f2bf(x0.w);
            t[4] = (short)f2bf(x1.x); t[5] = (short)f2bf(x1.y);
            t[6] = (short)f2bf(x1.z); t[7] = (short)f2bf(x1.w);
            af[ks] = t;
        }
        f32x4 acc[8];
        #pragma unroll
        for (int dt = 0; dt < 8; ++dt) acc[dt] = (f32x4){bv[dt], bv[dt], bv[dt], bv[dt]};
        #pragma unroll
        for (int ks = 0; ks < 4; ++ks) {
            #pragma unroll
            for (int dt = 0; dt < 8; ++dt) {
                bf16x8 bf = *(const bf16x8*)&WT[(size_t)(dt * 16 + la) * D + ks * 32 + kg * 8];
                acc[dt] = __builtin_amdgcn_mfma_f32_16x16x32_bf16(af[ks], bf, acc[dt], 0, 0, 0);
            }
        }
        // softmax tables from fp32 acc: s_atm[l] = atm[l][:] . wa
        float sr[4];
        #pragma unroll
        for (int r = 0; r < 4; ++r) {
            float t = 0.f;
            #pragma unroll
            for (int dt = 0; dt < 8; ++dt) t += acc[dt][r] * wav[dt];
            t += __shfl_xor(t, 1); t += __shfl_xor(t, 2);
            t += __shfl_xor(t, 4); t += __shfl_xor(t, 8);
            sr[r] = t;
        }
        if (la == 0) {
            #pragma unroll
            for (int r = 0; r < 4; ++r) {
                int l = l0 + lt + kg * 4 + r;
                float sm = smask[(size_t)b * L + l];
                bool val = sm > -0.5f;
                float sv = sr[r];
                s_atmM[(size_t)b * L + l] = val ? sv : -1e30f;
                e_l[(size_t)b * L + l]    = val ? __expf(sv) : 0.f;
                f_l[(size_t)b * L + l]    = val ? __expf(NEG_SLOPE * sv) : 0.f;
            }
        }
        // bf16 bounce into [d][l] tile (lane's 4 regs are consecutive l)
        #pragma unroll
        for (int dt = 0; dt < 8; ++dt) {
            union { ushort us[4]; uint2 v; } pk;
            #pragma unroll
            for (int r = 0; r < 4; ++r) pk.us[r] = f2bf(acc[dt][r]);
            *(uint2*)&tb[dt * 16 + la][lt + kg * 4] = pk.v;
        }
    }
    __syncthreads();
    {   // coalesced global write: atmT[b][d][l0..l0+127]
        const int d = tid >> 1, h = tid & 1;
        #pragma unroll
        for (int c = 0; c < 8; ++c) {
            int4 v = *(const int4*)&tb[d][h * 64 + c * 8];
            *(int4*)&atmT[((size_t)(b * 128 + d) << 10) + l0 + h * 64 + c * 8] = v;
        }
    }
}

// ---------------------------------------------------------------------------
// attn: block = (b, 64 fragment rows). Separable softmax, PV via MFMA,
// 2-deep register prefetch of atmT tiles (statically indexed pre0/pre1).
// ---------------------------------------------------------------------------
__global__ __launch_bounds__(256) void attn_kernel(
    const float* __restrict__ molf, const float* __restrict__ amask,
    const ushort* __restrict__ atmT,
    const float* __restrict__ s_atmM_g, const float* __restrict__ e_lG,
    const float* __restrict__ f_lG,
    const float* __restrict__ u, const float* __restrict__ c0p,
    const float* __restrict__ gamma, const float* __restrict__ beta,
    float* __restrict__ out) {
    __shared__ float sL[L], eL[L], fL[L];
    __shared__ float thL[64], eaL[64], faL[64];
    __shared__ float wmaxL[4];
    __shared__ float gbL[256];
    __shared__ int4 tileI[2][2048];                // 2 x 32 KB swizzled tiles

    const int bid = blockIdx.x;
    const int lid = (bid & 7) * 32 + (bid >> 3);   // XCD-bijective (256 % 8 == 0)
    const int b  = lid >> 2;
    const int at = lid & 3;
    const int tid = threadIdx.x;
    const int w = tid >> 6, lane = tid & 63;
    const int la = lane & 15, kg = lane >> 4;

    const ushort* atmTb = atmT + (size_t)b * D * L;
    const int c = tid & 15, db = tid >> 4;
    int4 pre0[8], pre1[8];

#define TLOAD(PRE, T)                                                          \
    _Pragma("unroll")                                                          \
    for (int j = 0; j < 8; ++j)                                                \
        PRE[j] = *(const int4*)&atmTb[(size_t)(db + j * 16) * L + (T) * 128 + c * 8];
#define TWRITE(PRE, BUF)                                                       \
    _Pragma("unroll")                                                          \
    for (int j = 0; j < 8; ++j) {                                              \
        int d_ = db + j * 16;                                                  \
        *(int4*)((char*)tileI[BUF] + d_ * 256 + sw16(d_, c) * 16) = PRE[j];    \
    }

    // issue first two tile loads before the scalar phases (latency overlap)
    TLOAD(pre0, 0)
    TLOAD(pre1, 1)

    // phase 0a: softmax tables -> LDS, gamma/beta, batch max M
    {
        int i4 = tid * 4;
        float4 sa = *(const float4*)&s_atmM_g[(size_t)b * L + i4];
        *(float4*)&sL[i4] = sa;
        *(float4*)&eL[i4] = *(const float4*)&e_lG[(size_t)b * L + i4];
        *(float4*)&fL[i4] = *(const float4*)&f_lG[(size_t)b * L + i4];
        if (tid < 32)      ((float4*)gbL)[tid] = ((const float4*)gamma)[tid];
        else if (tid < 64) ((float4*)gbL)[tid] = ((const float4*)beta)[tid - 32];
        float mx = fmaxf(fmaxf(sa.x, sa.y), fmaxf(sa.z, sa.w));
        #pragma unroll
        for (int o = 1; o < 64; o <<= 1) mx = fmaxf(mx, __shfl_xor(mx, o));
        if (lane == 0) wmaxL[w] = mx;
    }
    __syncthreads();

    // phase 0b: s_mol + per-row constants
    {
        float M = fmaxf(fmaxf(wmaxL[0], wmaxL[1]), fmaxf(wmaxL[2], wmaxL[3]));
        int r = tid >> 2, q = tid & 3;
        const float* x = molf + ((size_t)b * A + at * 64 + r) * D + q * 32;
        float p = 0.f;
        #pragma unroll
        for (int k = 0; k < 8; ++k) {
            float4 xv = *(const float4*)&x[k * 4];
            float4 uv = *(const float4*)&u[q * 32 + k * 4];
            p += xv.x * uv.x + xv.y * uv.y + xv.z * uv.z + xv.w * uv.w;
        }
        p += __shfl_xor(p, 1); p += __shfl_xor(p, 2);
        if (q == 0) {
            float sm = p + c0p[0];
            float z = sm + M;
            float m = (z > 0.f) ? z : NEG_SLOPE * z;
            thL[r] = -sm;
            eaL[r] = __expf(sm - m);
            faL[r] = __expf(NEG_SLOPE * sm - m);
        }
    }
    __syncthreads();

    const float ea = eaL[w * 16 + la];
    const float fa = faL[w * 16 + la];
    const float th = thL[w * 16 + la];
    f32x4 acc[8] = {};
    float psum = 0.f;

#define TCOMPUTE(BUF, T)                                                       \
    {                                                                          \
        const char* buf_ = (const char*)tileI[BUF];                            \
        _Pragma("unroll")                                                      \
        for (int ks = 0; ks < 4; ++ks) {                                       \
            int lbase = (T) * 128 + ks * 32 + kg * 8;                          \
            float sv[8], ev[8], fv[8];                                         \
            *(float4*)&sv[0] = *(const float4*)&sL[lbase];                     \
            *(float4*)&sv[4] = *(const float4*)&sL[lbase + 4];                 \
            *(float4*)&ev[0] = *(const float4*)&eL[lbase];                     \
            *(float4*)&ev[4] = *(const float4*)&eL[lbase + 4];                 \
            *(float4*)&fv[0] = *(const float4*)&fL[lbase];                     \
            *(float4*)&fv[4] = *(const float4*)&fL[lbase + 4];                 \
            bf16x8 bfrag;                                                      \
            _Pragma("unroll")                                                  \
            for (int j = 0; j < 8; ++j) {                                      \
                float p_ = (sv[j] > th) ? ea * ev[j] : fa * fv[j];             \
                psum += p_;                                                    \
                bfrag[j] = (short)f2bf(p_);                                    \
            }                                                                  \
            _Pragma("unroll")                                                  \
            for (int dt = 0; dt < 8; ++dt) {                                   \
                int d_ = dt * 16 + la;                                         \
                bf16x8 afrag = *(const bf16x8*)(buf_ + d_ * 256                \
                                                + sw16(d_, ks * 4 + kg) * 16); \
                acc[dt] = __builtin_amdgcn_mfma_f32_16x16x32_bf16(             \
                    afrag, bfrag, acc[dt], 0, 0, 0);                           \
            }                                                                  \
        }                                                                      \
    }

    #pragma unroll
    for (int tt = 0; tt < 4; ++tt) {
        TWRITE(pre0, 0)
        __syncthreads();
        if (tt < 3) { TLOAD(pre0, 2 * tt + 2) }
        TCOMPUTE(0, 2 * tt)
        TWRITE(pre1, 1)
        __syncthreads();
        if (tt < 3) { TLOAD(pre1, 2 * tt + 3) }
        TCOMPUTE(1, 2 * tt + 1)
    }

    // epilogue: normalize + attend mask + LayerNorm (in registers)
    psum += __shfl_xor(psum, 16);
    psum += __shfl_xor(psum, 32);
    const int aG = at * 64 + w * 16 + la;
    const float scale = amask[(size_t)b * A + aG] / psum;
    float v[8][4];
    float s1 = 0.f, s2 = 0.f;
    #pragma unroll
    for (int dt = 0; dt < 8; ++dt)
        #pragma unroll
        for (int r = 0; r < 4; ++r) {
            float x = acc[dt][r] * scale;
            v[dt][r] = x; s1 += x; s2 += x * x;
        }
    s1 += __shfl_xor(s1, 16); s1 += __shfl_xor(s1, 32);
    s2 += __shfl_xor(s2, 16); s2 += __shfl_xor(s2, 32);
    const float mu = s1 * (1.f / 128.f);
    const float var = s2 * (1.f / 128.f) - mu * mu;
    const float rs = rsqrtf(var + LN_EPS);
    const size_t obase = ((size_t)b * A + aG) * D;
    #pragma unroll
    for (int dt = 0; dt < 8; ++dt) {
        int d0 = dt * 16 + kg * 4;
        float4 g4 = *(float4*)&gbL[d0];
        float4 b4 = *(float4*)&gbL[128 + d0];
        float4 o;
        o.x = (v[dt][0] - mu) * rs * g4.x + b4.x;
        o.y = (v[dt][1] - mu) * rs * g4.y + b4.y;
        o.z = (v[dt][2] - mu) * rs * g4.z + b4.z;
        o.w = (v[dt][3] - mu) * rs * g4.w + b4.w;
        *(float4*)&out[obase + d0] = o;
    }
#undef TLOAD
#undef TWRITE
#undef TCOMPUTE
}

// ---------------------------------------------------------------------------
extern "C" void kernel_launch(void* const* d_in, const int* in_sizes, int n_in,
                              void* d_out, int out_size, void* d_ws, size_t ws_size,
                              hipStream_t stream) {
    const float* molf  = (const float*)d_in[0];
    const float* atomf = (const float*)d_in[1];
    const float* amask = (const float*)d_in[2];
    const float* smask = (const float*)d_in[3];
    const float* W_mol = (const float*)d_in[4];
    const float* b_mol = (const float*)d_in[5];
    const float* W_nb  = (const float*)d_in[6];
    const float* b_nb  = (const float*)d_in[7];
    const float* w_am  = (const float*)d_in[8];
    const float* w_aa  = (const float*)d_in[9];
    const float* b_al  = (const float*)d_in[10];
    const float* gamma = (const float*)d_in[11];
    const float* beta  = (const float*)d_in[12];
    float* out = (float*)d_out;

    // ws: atmT bf16 [B*D*L] | s_atmM | e_l | f_l [B*L] | u [D] | c0 | WT bf16 [D*D]
    ushort* atmT   = (ushort*)d_ws;
    float* s_atmM  = (float*)(atmT + (size_t)B * D * L);
    float* e_l     = s_atmM + (size_t)B * L;
    float* f_l     = e_l + (size_t)B * L;
    float* u_ws    = f_l + (size_t)B * L;
    float* c0_ws   = u_ws + D;
    ushort* WT     = (ushort*)(c0_ws + 1);

    prep_kernel<<<128, 128, 0, stream>>>(W_mol, b_mol, w_am, b_al, W_nb,
                                         u_ws, c0_ws, WT);
    nb_gemm_kernel<<<(B * L) / 128, 256, 0, stream>>>(atomf, WT, b_nb, w_aa,
                                                      smask, atmT, s_atmM, e_l, f_l);
    attn_kernel<<<B * (A / 64), 256, 0, stream>>>(molf, amask, atmT, s_atmM, e_l,
                                                  f_l, u_ws, c0_ws, gamma, beta, out);
}

// Round 4
// 71.571 us; speedup vs baseline: 2.4015x; 1.1254x over previous
//
#include <hip/hip_runtime.h>
#include <hip/hip_bf16.h>
#include <math.h>

#define NEG_SLOPE 0.2f
#define LN_EPS 1e-5f

constexpr int B = 64, A = 256, L = 1024, D = 128;

typedef float f32x4 __attribute__((ext_vector_type(4)));
typedef short bf16x8 __attribute__((ext_vector_type(8)));

__device__ __forceinline__ ushort f2bf(float x) {
    __hip_bfloat16 h = __float2bfloat16(x);
    return *reinterpret_cast<ushort*>(&h);
}

// ---------------------------------------------------------------------------
// prep: u = W_mol @ w_align_mol ; c0 = b_mol.w_align_mol + b_align ;
//       WT[d][e] = bf16(W_nb[e][d])
// ---------------------------------------------------------------------------
__global__ void prep_kernel(const float* __restrict__ Wmol, const float* __restrict__ bmol,
                            const float* __restrict__ wam, const float* __restrict__ bal,
                            const float* __restrict__ Wnb,
                            float* __restrict__ u, float* __restrict__ c0,
                            ushort* __restrict__ WT) {
    __shared__ float red[2], red2[2];
    const int d = blockIdx.x, e = threadIdx.x;   // 128 blocks x 128 threads
    const int lane = e & 63, wv = e >> 6;
    float p = Wmol[d * D + e] * wam[e];
    #pragma unroll
    for (int o = 1; o < 64; o <<= 1) p += __shfl_xor(p, o);
    WT[d * D + e] = f2bf(Wnb[e * D + d]);
    float q = 0.f;
    if (d == 0) q = bmol[e] * wam[e];
    #pragma unroll
    for (int o = 1; o < 64; o <<= 1) q += __shfl_xor(q, o);
    if (lane == 0) { red[wv] = p; red2[wv] = q; }
    __syncthreads();
    if (e == 0) {
        u[d] = red[0] + red[1];
        if (d == 0) c0[0] = red2[0] + red2[1] + bal[0];
    }
}

// ---------------------------------------------------------------------------
// nb_gemm v5: 2048 blocks x 128 thr (2 waves), 32 l-rows per block.
// Wave wv handles 16 rows: A = atom rows (fp32->bf16 regs), B = WT (L1-hot).
// C[l][d]: col la = d-frag, row kg*4+r = l-frag. Epilogue: tables + bounce.
// ---------------------------------------------------------------------------
__global__ __launch_bounds__(128, 4) void nb_gemm_kernel(
    const float* __restrict__ atom, const ushort* __restrict__ WT,
    const float* __restrict__ bias, const float* __restrict__ wa,
    const float* __restrict__ smask,
    ushort* __restrict__ atmT, float* __restrict__ s_atmM,
    float* __restrict__ e_l, float* __restrict__ f_l) {
    __shared__ ushort tb[128][36];   // [d][l-local], padded
    const int tid = threadIdx.x;
    const int wv = tid >> 6, lane = tid & 63, la = lane & 15, kg = lane >> 4;
    const int R0 = blockIdx.x * 32;
    const int b = R0 >> 10, l0 = R0 & 1023;
    const int row = R0 + wv * 16 + la;

    // A fragments: this lane's atom row, fp32 -> bf16
    const float* arow = atom + (size_t)row * D + kg * 8;
    bf16x8 af[4];
    #pragma unroll
    for (int ks = 0; ks < 4; ++ks) {
        float4 x0 = *(const float4*)&arow[ks * 32];
        float4 x1 = *(const float4*)&arow[ks * 32 + 4];
        bf16x8 t;
        t[0] = (short)f2bf(x0.x); t[1] = (short)f2bf(x0.y);
        t[2] = (short)f2bf(x0.z); t[3] = (short)f2bf(x0.w);
        t[4] = (short)f2bf(x1.x); t[5] = (short)f2bf(x1.y);
        t[6] = (short)f2bf(x1.z); t[7] = (short)f2bf(x1.w);
        af[ks] = t;
    }
    float wav[8], bv[8];
    #pragma unroll
    for (int dt = 0; dt < 8; ++dt) { wav[dt] = wa[dt * 16 + la]; bv[dt] = bias[dt * 16 + la]; }

    f32x4 acc[8];
    #pragma unroll
    for (int dt = 0; dt < 8; ++dt) acc[dt] = (f32x4){bv[dt], bv[dt], bv[dt], bv[dt]};
    #pragma unroll
    for (int ks = 0; ks < 4; ++ks) {
        #pragma unroll
        for (int dt = 0; dt < 8; ++dt) {
            bf16x8 bf = *(const bf16x8*)&WT[(size_t)(dt * 16 + la) * D + ks * 32 + kg * 8];
            acc[dt] = __builtin_amdgcn_mfma_f32_16x16x32_bf16(af[ks], bf, acc[dt], 0, 0, 0);
        }
    }

    // softmax tables: s_atm[l] = atm[l][:] . wa  (fp32 acc)
    float sr[4];
    #pragma unroll
    for (int r = 0; r < 4; ++r) {
        float t = 0.f;
        #pragma unroll
        for (int dt = 0; dt < 8; ++dt) t += acc[dt][r] * wav[dt];
        t += __shfl_xor(t, 1); t += __shfl_xor(t, 2);
        t += __shfl_xor(t, 4); t += __shfl_xor(t, 8);
        sr[r] = t;
    }
    if (la == 0) {
        #pragma unroll
        for (int r = 0; r < 4; ++r) {
            int l = l0 + wv * 16 + kg * 4 + r;
            float sm = smask[(size_t)b * L + l];
            bool val = sm > -0.5f;
            float sv = sr[r];
            s_atmM[(size_t)b * L + l] = val ? sv : -1e30f;
            e_l[(size_t)b * L + l]    = val ? __expf(sv) : 0.f;
            f_l[(size_t)b * L + l]    = val ? __expf(NEG_SLOPE * sv) : 0.f;
        }
    }
    // bf16 bounce to [d][l-local]
    #pragma unroll
    for (int dt = 0; dt < 8; ++dt) {
        union { ushort us[4]; uint2 v; } pk;
        #pragma unroll
        for (int r = 0; r < 4; ++r) pk.us[r] = f2bf(acc[dt][r]);
        *(uint2*)&tb[dt * 16 + la][wv * 16 + kg * 4] = pk.v;
    }
    __syncthreads();
    // line-coalesced write: lanes (c fast, d slow) -> contiguous 64B per d-row
    {
        const int c = tid & 3, dd = tid >> 2;   // c: 16B chunk, dd: 0..31
        #pragma unroll
        for (int j = 0; j < 4; ++j) {
            int d = dd + j * 32;
            *(int4*)&atmT[((size_t)(b * 128 + d) << 10) + l0 + c * 8] =
                *(const int4*)&tb[d][c * 8];
        }
    }
}

// ---------------------------------------------------------------------------
// attn v5: 1024 blocks (b, 16 a-rows), 256 thr = 4 waves; wave = L-quarter.
// No LDS atm tile, no main-loop barriers: A-frags read b128 直接 from global
// (L2/L3-resident atmT). Separable softmax tables in LDS. Epilogue combines
// the 4 L-partial accumulators via ctxL + fused LayerNorm.
// ---------------------------------------------------------------------------
__global__ __launch_bounds__(256, 3) void attn_kernel(
    const float* __restrict__ molf, const float* __restrict__ amask,
    const ushort* __restrict__ atmT,
    const float* __restrict__ s_atmM_g, const float* __restrict__ e_lG,
    const float* __restrict__ f_lG,
    const float* __restrict__ u, const float* __restrict__ c0p,
    const float* __restrict__ gamma, const float* __restrict__ beta,
    float* __restrict__ out) {
    __shared__ float sL[L], eL[L], fL[L];          // 12 KB tables
    __shared__ float thL[16], eaL[16], faL[16];
    __shared__ float wmaxL[4];
    __shared__ float psums[4][16];
    __shared__ float gbL[256];
    __shared__ float ctxL[16][132];                // [a][d], padded

    const int bid = blockIdx.x;
    const int lid = (bid & 7) * 128 + (bid >> 3);  // XCD-bijective (1024 % 8 == 0)
    const int b  = lid >> 4;
    const int at = lid & 15;
    const int tid = threadIdx.x;
    const int w = tid >> 6, lane = tid & 63;
    const int la = lane & 15, kg = lane >> 4;

    // phase 1: tables + gamma/beta + batch max M
    {
        int i4 = tid * 4;
        float4 sa = *(const float4*)&s_atmM_g[(size_t)b * L + i4];
        *(float4*)&sL[i4] = sa;
        *(float4*)&eL[i4] = *(const float4*)&e_lG[(size_t)b * L + i4];
        *(float4*)&fL[i4] = *(const float4*)&f_lG[(size_t)b * L + i4];
        if (tid < 32)      ((float4*)gbL)[tid] = ((const float4*)gamma)[tid];
        else if (tid < 64) ((float4*)gbL)[tid] = ((const float4*)beta)[tid - 32];
        float mx = fmaxf(fmaxf(sa.x, sa.y), fmaxf(sa.z, sa.w));
        #pragma unroll
        for (int o = 1; o < 64; o <<= 1) mx = fmaxf(mx, __shfl_xor(mx, o));
        if (lane == 0) wmaxL[w] = mx;
    }
    __syncthreads();

    // phase 2: s_mol + per-row constants (thread = (r = tid>>4, q = tid&15))
    {
        float M = fmaxf(fmaxf(wmaxL[0], wmaxL[1]), fmaxf(wmaxL[2], wmaxL[3]));
        int r = tid >> 4, q = tid & 15;
        const float* x = molf + ((size_t)b * A + at * 16 + r) * D + q * 8;
        float4 xa = *(const float4*)x;
        float4 xb = *(const float4*)(x + 4);
        float4 ua = *(const float4*)&u[q * 8];
        float4 ub = *(const float4*)&u[q * 8 + 4];
        float p = xa.x * ua.x + xa.y * ua.y + xa.z * ua.z + xa.w * ua.w
                + xb.x * ub.x + xb.y * ub.y + xb.z * ub.z + xb.w * ub.w;
        p += __shfl_xor(p, 1); p += __shfl_xor(p, 2);
        p += __shfl_xor(p, 4); p += __shfl_xor(p, 8);
        if (q == 0) {
            float sm = p + c0p[0];
            float z = sm + M;
            float m = (z > 0.f) ? z : NEG_SLOPE * z;   // exact row max
            thL[r] = -sm;
            eaL[r] = __expf(sm - m);
            faL[r] = __expf(NEG_SLOPE * sm - m);
        }
    }
    __syncthreads();

    // main loop: wave w handles l in [w*256, (w+1)*256): 2 tiles of 128
    const float ea = eaL[la], fa = faL[la], th = thL[la];
    const ushort* atmTb = atmT + (size_t)b * D * L;
    f32x4 acc[8] = {};
    float psum = 0.f;

    #pragma unroll
    for (int tt = 0; tt < 2; ++tt) {
        const int t = w * 2 + tt;
        #pragma unroll
        for (int ks = 0; ks < 4; ++ks) {
            const int lbase = t * 128 + ks * 32 + kg * 8;
            float4 s0 = *(const float4*)&sL[lbase];
            float4 s1 = *(const float4*)&sL[lbase + 4];
            float4 e0 = *(const float4*)&eL[lbase];
            float4 e1 = *(const float4*)&eL[lbase + 4];
            float4 f0 = *(const float4*)&fL[lbase];
            float4 f1 = *(const float4*)&fL[lbase + 4];
            bf16x8 bfrag;
            float p0 = (s0.x > th) ? ea * e0.x : fa * f0.x;
            float p1 = (s0.y > th) ? ea * e0.y : fa * f0.y;
            float p2 = (s0.z > th) ? ea * e0.z : fa * f0.z;
            float p3 = (s0.w > th) ? ea * e0.w : fa * f0.w;
            float p4 = (s1.x > th) ? ea * e1.x : fa * f1.x;
            float p5 = (s1.y > th) ? ea * e1.y : fa * f1.y;
            float p6 = (s1.z > th) ? ea * e1.z : fa * f1.z;
            float p7 = (s1.w > th) ? ea * e1.w : fa * f1.w;
            psum += (p0 + p1) + (p2 + p3) + ((p4 + p5) + (p6 + p7));
            bfrag[0] = (short)f2bf(p0); bfrag[1] = (short)f2bf(p1);
            bfrag[2] = (short)f2bf(p2); bfrag[3] = (short)f2bf(p3);
            bfrag[4] = (short)f2bf(p4); bfrag[5] = (short)f2bf(p5);
            bfrag[6] = (short)f2bf(p6); bfrag[7] = (short)f2bf(p7);
            #pragma unroll
            for (int dt = 0; dt < 8; ++dt) {
                bf16x8 afrag = *(const bf16x8*)&atmTb[(size_t)(dt * 16 + la) * L + lbase];
                acc[dt] = __builtin_amdgcn_mfma_f32_16x16x32_bf16(afrag, bfrag, acc[dt], 0, 0, 0);
            }
        }
    }

    // psum: reduce over kg, publish per wave
    psum += __shfl_xor(psum, 16);
    psum += __shfl_xor(psum, 32);
    if (lane < 16) psums[w][la] = psum;

    // combine the 4 L-partial accumulators into ctxL (4 rounds, static idx)
    #pragma unroll
    for (int p = 0; p < 4; ++p) {
        if (w == p) {
            #pragma unroll
            for (int dt = 0; dt < 8; ++dt)
                #pragma unroll
                for (int r = 0; r < 4; ++r) {
                    int d = dt * 16 + kg * 4 + r;
                    if (p == 0) ctxL[la][d] = acc[dt][r];
                    else        ctxL[la][d] += acc[dt][r];
                }
        }
        __syncthreads();
    }

    // LayerNorm: thread = (r = tid>>4, c = tid&15), 8 d's each
    {
        int r = tid >> 4, c = tid & 15;
        float inv = psums[0][r] + psums[1][r] + psums[2][r] + psums[3][r];
        float sc = amask[(size_t)b * A + at * 16 + r] / inv;
        float x[8];
        float s1 = 0.f, s2 = 0.f;
        #pragma unroll
        for (int i = 0; i < 8; ++i) {
            x[i] = ctxL[r][c * 8 + i] * sc;
            s1 += x[i]; s2 += x[i] * x[i];
        }
        s1 += __shfl_xor(s1, 1); s2 += __shfl_xor(s2, 1);
        s1 += __shfl_xor(s1, 2); s2 += __shfl_xor(s2, 2);
        s1 += __shfl_xor(s1, 4); s2 += __shfl_xor(s2, 4);
        s1 += __shfl_xor(s1, 8); s2 += __shfl_xor(s2, 8);
        float mu = s1 * (1.f / 128.f);
        float var = s2 * (1.f / 128.f) - mu * mu;
        float rs = rsqrtf(var + LN_EPS);
        float4 o0, o1;
        float* op = (float*)&o0;
        #pragma unroll
        for (int i = 0; i < 8; ++i) {
            float y = (x[i] - mu) * rs * gbL[c * 8 + i] + gbL[128 + c * 8 + i];
            if (i < 4) ((float*)&o0)[i] = y; else ((float*)&o1)[i - 4] = y;
        }
        (void)op;
        size_t base = ((size_t)b * A + at * 16 + r) * D + c * 8;
        *(float4*)&out[base]     = o0;
        *(float4*)&out[base + 4] = o1;
    }
}

// ---------------------------------------------------------------------------
extern "C" void kernel_launch(void* const* d_in, const int* in_sizes, int n_in,
                              void* d_out, int out_size, void* d_ws, size_t ws_size,
                              hipStream_t stream) {
    const float* molf  = (const float*)d_in[0];
    const float* atomf = (const float*)d_in[1];
    const float* amask = (const float*)d_in[2];
    const float* smask = (const float*)d_in[3];
    const float* W_mol = (const float*)d_in[4];
    const float* b_mol = (const float*)d_in[5];
    const float* W_nb  = (const float*)d_in[6];
    const float* b_nb  = (const float*)d_in[7];
    const float* w_am  = (const float*)d_in[8];
    const float* w_aa  = (const float*)d_in[9];
    const float* b_al  = (const float*)d_in[10];
    const float* gamma = (const float*)d_in[11];
    const float* beta  = (const float*)d_in[12];
    float* out = (float*)d_out;

    // ws: atmT bf16 [B*D*L] | s_atmM | e_l | f_l [B*L] | u [D] | c0 | WT bf16 [D*D]
    ushort* atmT   = (ushort*)d_ws;
    float* s_atmM  = (float*)(atmT + (size_t)B * D * L);
    float* e_l     = s_atmM + (size_t)B * L;
    float* f_l     = e_l + (size_t)B * L;
    float* u_ws    = f_l + (size_t)B * L;
    float* c0_ws   = u_ws + D;
    ushort* WT     = (ushort*)(c0_ws + 1);

    prep_kernel<<<128, 128, 0, stream>>>(W_mol, b_mol, w_am, b_al, W_nb,
                                         u_ws, c0_ws, WT);
    nb_gemm_kernel<<<(B * L) / 32, 128, 0, stream>>>(atomf, WT, b_nb, w_aa,
                                                     smask, atmT, s_atmM, e_l, f_l);
    attn_kernel<<<B * (A / 16), 256, 0, stream>>>(molf, amask, atmT, s_atmM, e_l,
                                                  f_l, u_ws, c0_ws, gamma, beta, out);
}